// Round 9
// baseline (1409.470 us; speedup 1.0000x reference)
//
#include <hip/hip_runtime.h>

// r9: wave-split dense kernels. r8 post-mortem: lane-per-node MLP is
// grid-starved (N/64 waves = 1.5/SIMD, Occupancy 23%) and latency-bound on
// wave-uniform weight s_loads (1 weight dword : 1 FMA, VALUBusy 22%).
// Split each node across 2 waves (half the outputs each), exchange partials
// via swizzled LDS (col ^ 4*(lane&7) -> conflict-optimal b128). Weights stay
// wave-uniform (hf is per-wave). 2x waves, half FMAs/thread.

typedef unsigned int uint;

__device__ __forceinline__ uint f2bf(float a) {     // RNE f32->bf16 (finite)
    uint u = __float_as_uint(a);
    return (u + 0x7fffu + ((u >> 16) & 1u)) >> 16;
}

#define SWZ(l, c) ((c) ^ (((l) & 7) << 2))

// ---------------- fused stage 1: node MLP (wave-split) || histograms || prep --
__global__ __attribute__((amdgpu_waves_per_eu(3, 3))) void __launch_bounds__(256)
k_fused1(const float* __restrict__ x,
         const float* __restrict__ faW1, const float* __restrict__ fab1,
         const float* __restrict__ faW2, const float* __restrict__ fab2,
         const float* __restrict__ projW, const float* __restrict__ projb,
         float* __restrict__ hbuf, int N,
         const int* __restrict__ ei, int E,
         float* __restrict__ deg, int* __restrict__ cnt,
         const float* __restrict__ seW2, const float* __restrict__ seb2,
         const float* __restrict__ oW1, const float* __restrict__ ob1,
         float* __restrict__ M2, float* __restrict__ b2f,
         int gMlp, int gEdge) {
    int bid = blockIdx.x;
    if (bid < gMlp) {
        // 128 nodes/block: 2 groups x 64 nodes; 2 waves per group (hf = j/i half)
        __shared__ float lds[2][64][64];   // 32 KB
        int tid  = threadIdx.x;
        int wave = tid >> 6, lane = tid & 63;
        int g = wave >> 1, hf = wave & 1;
        int n = bid * 128 + g * 64 + lane;
        int nc = n < N ? n : N - 1;
        const float* xr = x + (size_t)nc * 128;
        float* row = &lds[g][lane][0];

        // ---- stage 1: t_part[32] = relu-pre (own j-half) ----
        float tp[32];
        const float* w1 = faW1 + hf * 32;
#pragma unroll
        for (int j = 0; j < 32; ++j) tp[j] = fab1[hf * 32 + j];
#pragma unroll 2
        for (int c = 0; c < 32; ++c) {
            float4 xv = *reinterpret_cast<const float4*>(xr + c * 4);
            const float* wb = w1 + c * 4 * 64;
#pragma unroll
            for (int j = 0; j < 32; ++j) {
                tp[j] = fmaf(xv.x, wb[j], tp[j]);
                tp[j] = fmaf(xv.y, wb[64 + j], tp[j]);
                tp[j] = fmaf(xv.z, wb[128 + j], tp[j]);
                tp[j] = fmaf(xv.w, wb[192 + j], tp[j]);
            }
        }
#pragma unroll
        for (int q = 0; q < 8; ++q) {
            float4 v = make_float4(fmaxf(tp[q * 4], 0.f), fmaxf(tp[q * 4 + 1], 0.f),
                                   fmaxf(tp[q * 4 + 2], 0.f), fmaxf(tp[q * 4 + 3], 0.f));
            *reinterpret_cast<float4*>(row + SWZ(lane, hf * 32 + q * 4)) = v;
        }
        __syncthreads();

        // ---- full t row into registers ----
        float t[64];
#pragma unroll
        for (int q = 0; q < 16; ++q) {
            float4 v = *reinterpret_cast<const float4*>(row + SWZ(lane, q * 4));
            t[q * 4] = v.x; t[q * 4 + 1] = v.y; t[q * 4 + 2] = v.z; t[q * 4 + 3] = v.w;
        }
        __syncthreads();   // all t-reads done before lds reused for h

        // ---- stage 2: own i-half: f_i, xm_i, h_part ----
        float hp[64];
#pragma unroll
        for (int j = 0; j < 64; ++j) hp[j] = 0.f;
#pragma unroll 2
        for (int c = 0; c < 16; ++c) {
            int i0 = hf * 64 + c * 4;
            float4 xv = *reinterpret_cast<const float4*>(xr + i0);
            const float* w2 = faW2 + i0;
            float f0 = fab2[i0], f1 = fab2[i0 + 1], f2 = fab2[i0 + 2], f3 = fab2[i0 + 3];
#pragma unroll
            for (int j = 0; j < 64; ++j) {
                float tj = t[j];
                f0 = fmaf(tj, w2[j * 128], f0);
                f1 = fmaf(tj, w2[j * 128 + 1], f1);
                f2 = fmaf(tj, w2[j * 128 + 2], f2);
                f3 = fmaf(tj, w2[j * 128 + 3], f3);
            }
            float xm0 = xv.x / (1.f + __expf(-f0));
            float xm1 = xv.y / (1.f + __expf(-f1));
            float xm2 = xv.z / (1.f + __expf(-f2));
            float xm3 = xv.w / (1.f + __expf(-f3));
            const float* wp = projW + i0 * 64;
#pragma unroll
            for (int j = 0; j < 64; ++j) {
                hp[j] = fmaf(xm0, wp[j], hp[j]);
                hp[j] = fmaf(xm1, wp[64 + j], hp[j]);
                hp[j] = fmaf(xm2, wp[128 + j], hp[j]);
                hp[j] = fmaf(xm3, wp[192 + j], hp[j]);
            }
        }
        // ---- combine halves: hf0 writes partial, hf1 adds + stores ----
        if (hf == 0) {
#pragma unroll
            for (int q = 0; q < 16; ++q)
                *reinterpret_cast<float4*>(row + SWZ(lane, q * 4)) =
                    make_float4(hp[q * 4], hp[q * 4 + 1], hp[q * 4 + 2], hp[q * 4 + 3]);
        }
        __syncthreads();
        if (hf == 1 && n < N) {
            float* hr = hbuf + (size_t)n * 64;
#pragma unroll
            for (int q = 0; q < 16; ++q) {
                float4 p = *reinterpret_cast<const float4*>(row + SWZ(lane, q * 4));
                float4 v = make_float4(hp[q * 4] + p.x + projb[q * 4],
                                       hp[q * 4 + 1] + p.y + projb[q * 4 + 1],
                                       hp[q * 4 + 2] + p.z + projb[q * 4 + 2],
                                       hp[q * 4 + 3] + p.w + projb[q * 4 + 3]);
                *reinterpret_cast<float4*>(hr + q * 4) = v;
            }
        }
    } else if (bid < gMlp + gEdge) {
        int e = (bid - gMlp) * blockDim.x + threadIdx.x;
        if (e < E) {
            atomicAdd(&deg[ei[e]], 1.f);
            atomicAdd(&cnt[ei[E + e]], 1);
        }
    } else {
        int tid = threadIdx.x;
        for (int o = tid; o < 32 * 64; o += 256) {
            int k = o >> 6, j = o & 63;
            float s = 0.f;
            for (int i = 0; i < 64; ++i)
                s = fmaf(seW2[k * 64 + i], oW1[(64 + i) * 64 + j], s);
            M2[o] = s;
        }
        for (int j = tid; j < 64; j += 256) {
            float s = ob1[j];
            for (int i = 0; i < 64; ++i)
                s = fmaf(seb2[i], oW1[(64 + i) * 64 + j], s);
            b2f[j] = s;
        }
    }
}

// ---------------- CSR alloc (+self-loop at slot 0) ----------------
__global__ void k_alloc(const int* __restrict__ cnt, int* __restrict__ startp,
                        int* __restrict__ esrc, int* __restrict__ gcur, int N) {
    int idx  = blockIdx.x * blockDim.x + threadIdx.x;
    int lane = threadIdx.x & 63;
    int c = idx < N ? cnt[idx] + 1 : 0;
    int sc = c;
#pragma unroll
    for (int off = 1; off < 64; off <<= 1) {
        int t = __shfl_up(sc, off, 64);
        if (lane >= off) sc += t;
    }
    int base = 0;
    if (lane == 63) base = atomicAdd(gcur, sc);
    base = __shfl(base, 63, 64);
    if (idx < N) {
        int st = base + sc - c;
        startp[idx] = st;
        esrc[st] = idx;
    }
}

// ---------------- CSR fill + inflsum (one edge pass) ----------------
__global__ void k_fill(const int* __restrict__ ei, int E,
                       const int* __restrict__ startp, int* __restrict__ cursor,
                       int* __restrict__ esrc,
                       const float* __restrict__ deg, float* __restrict__ inflsum) {
    int e = blockIdx.x * blockDim.x + threadIdx.x;
    if (e >= E) return;
    int s = ei[e], d = ei[E + e];
    int p = atomicAdd(&cursor[d], 1);
    esrc[startp[d] + 1 + p] = s;
    atomicAdd(&inflsum[s], deg[d]);
}

// ---------------- GAT z (wave-split GEMV) + es/ed; || infl rider ------------
__global__ __attribute__((amdgpu_waves_per_eu(4, 4))) void __launch_bounds__(256)
k_z(const float* __restrict__ hbuf, const float* __restrict__ W,
    const float* __restrict__ asrc, const float* __restrict__ adst,
    uint* __restrict__ zbuf, float* __restrict__ es, float* __restrict__ ed,
    const float* __restrict__ deg, const float* __restrict__ inflsum,
    float* __restrict__ inflv, unsigned* __restrict__ scal,
    int N, int gZ) {
    int bid = blockIdx.x;
    if (bid >= gZ) {
        // structural infl + global maxes (rides on first layer only)
        int idx = (bid - gZ) * blockDim.x + threadIdx.x;
        float dv = 0.f, iv = 0.f;
        if (idx < N) {
            dv = deg[idx];
            iv = dv > 0.f ? inflsum[idx] / dv : 0.f;
            inflv[idx] = iv;
        }
        float dm = dv, im = iv;
#pragma unroll
        for (int off = 32; off; off >>= 1) {
            dm = fmaxf(dm, __shfl_xor(dm, off, 64));
            im = fmaxf(im, __shfl_xor(im, off, 64));
        }
        if ((threadIdx.x & 63) == 0) {
            atomicMax(scal + 0, __float_as_uint(dm));
            atomicMax(scal + 1, __float_as_uint(im));
        }
        return;
    }
    __shared__ float lds[2][64][64];   // 32 KB
    int tid  = threadIdx.x;
    int wave = tid >> 6, lane = tid & 63;
    int g = wave >> 1, hf = wave & 1;
    int n = bid * 128 + g * 64 + lane;
    int nc = n < N ? n : N - 1;
    const float* hr = hbuf + (size_t)nc * 64 + hf * 32;
    float* row = &lds[g][lane][0];

    float zp[64];
#pragma unroll
    for (int j = 0; j < 64; ++j) zp[j] = 0.f;
#pragma unroll 2
    for (int c = 0; c < 8; ++c) {
        float4 hv = *reinterpret_cast<const float4*>(hr + c * 4);
        const float* wb = W + (hf * 32 + c * 4) * 64;
#pragma unroll
        for (int j = 0; j < 64; ++j) {
            zp[j] = fmaf(hv.x, wb[j], zp[j]);
            zp[j] = fmaf(hv.y, wb[64 + j], zp[j]);
            zp[j] = fmaf(hv.z, wb[128 + j], zp[j]);
            zp[j] = fmaf(hv.w, wb[192 + j], zp[j]);
        }
    }
    if (hf == 0) {
#pragma unroll
        for (int q = 0; q < 16; ++q)
            *reinterpret_cast<float4*>(row + SWZ(lane, q * 4)) =
                make_float4(zp[q * 4], zp[q * 4 + 1], zp[q * 4 + 2], zp[q * 4 + 3]);
    }
    __syncthreads();
    if (hf == 1 && n < N) {
        float z[64];
#pragma unroll
        for (int q = 0; q < 16; ++q) {
            float4 p = *reinterpret_cast<const float4*>(row + SWZ(lane, q * 4));
            z[q * 4] = zp[q * 4] + p.x;
            z[q * 4 + 1] = zp[q * 4 + 1] + p.y;
            z[q * 4 + 2] = zp[q * 4 + 2] + p.z;
            z[q * 4 + 3] = zp[q * 4 + 3] + p.w;
        }
        uint* zr = zbuf + (size_t)n * 32;
#pragma unroll
        for (int c = 0; c < 8; ++c) {
            uint4 pv;
            pv.x = f2bf(z[c * 8 + 0]) | (f2bf(z[c * 8 + 1]) << 16);
            pv.y = f2bf(z[c * 8 + 2]) | (f2bf(z[c * 8 + 3]) << 16);
            pv.z = f2bf(z[c * 8 + 4]) | (f2bf(z[c * 8 + 5]) << 16);
            pv.w = f2bf(z[c * 8 + 6]) | (f2bf(z[c * 8 + 7]) << 16);
            *reinterpret_cast<uint4*>(zr + c * 4) = pv;
        }
        float e0 = 0, e1 = 0, e2 = 0, e3 = 0, d0 = 0, d1 = 0, d2 = 0, d3 = 0;
#pragma unroll
        for (int j = 0; j < 64; j += 4) {
            e0 = fmaf(z[j], asrc[j], e0);
            e1 = fmaf(z[j + 1], asrc[j + 1], e1);
            e2 = fmaf(z[j + 2], asrc[j + 2], e2);
            e3 = fmaf(z[j + 3], asrc[j + 3], e3);
            d0 = fmaf(z[j], adst[j], d0);
            d1 = fmaf(z[j + 1], adst[j + 1], d1);
            d2 = fmaf(z[j + 2], adst[j + 2], d2);
            d3 = fmaf(z[j + 3], adst[j + 3], d3);
        }
        es[n] = (e0 + e1) + (e2 + e3);
        ed[n] = (d0 + d1) + (d2 + d3);
    }
}

// ---------------- fused GAT aggregation: dual-edge half-wave (bf16 z) --------
__global__ void k_agg(const int* __restrict__ start, const int* __restrict__ cnt,
                      const int* __restrict__ esrc,
                      const float* __restrict__ es, const float* __restrict__ ed,
                      const uint* __restrict__ zb,
                      const float* __restrict__ b, const float* __restrict__ g,
                      const float* __restrict__ bta, const float* __restrict__ mean,
                      const float* __restrict__ var,
                      float* __restrict__ hbuf, int N) {
    int wid  = (blockIdx.x * blockDim.x + threadIdx.x) >> 6;
    int lane = threadIdx.x & 63;
    if (wid >= N) return;
    int row0 = start[wid];
    int c    = cnt[wid] + 1;
    float edn = ed[wid];
    int lk = lane & 31, half = lane >> 5;

    int   sreg = 0;
    float exv  = 0.f;
    if (lane < c) {
        sreg = esrc[row0 + lane];
        float e = es[sreg] + edn;
        e = e >= 0.f ? e : 0.2f * e;
        exv = __expf(e);
    }
    float ssum = exv;
    for (int k = 64 + lane; k < c; k += 64) {
        int s = esrc[row0 + k];
        float e = es[s] + edn; e = e >= 0.f ? e : 0.2f * e;
        ssum += __expf(e);
    }
#pragma unroll
    for (int off = 32; off; off >>= 1) ssum += __shfl_xor(ssum, off, 64);

    float acc0 = 0.f, acc1 = 0.f;
    int kmax = c < 64 ? c : 64;
    for (int e = half; e < kmax; e += 2) {
        int   se = __shfl(sreg, e, 64);
        float we = __shfl(exv, e, 64);
        uint p = zb[(size_t)se * 32 + lk];
        acc0 = fmaf(__uint_as_float(p << 16), we, acc0);
        acc1 = fmaf(__uint_as_float(p & 0xffff0000u), we, acc1);
    }
    for (int e = 64; e < c; ++e) {
        int s = esrc[row0 + e];
        float ee = es[s] + edn; ee = ee >= 0.f ? ee : 0.2f * ee;
        float we = __expf(ee);
        if (half == 0) {
            uint p = zb[(size_t)s * 32 + lk];
            acc0 = fmaf(__uint_as_float(p << 16), we, acc0);
            acc1 = fmaf(__uint_as_float(p & 0xffff0000u), we, acc1);
        }
    }
    acc0 += __shfl_xor(acc0, 32, 64);
    acc1 += __shfl_xor(acc1, 32, 64);

    if (half == 0) {
        float inv = 1.f / ssum;
        float2 bb = reinterpret_cast<const float2*>(b)[lk];
        float2 gg = reinterpret_cast<const float2*>(g)[lk];
        float2 tt = reinterpret_cast<const float2*>(bta)[lk];
        float2 mm = reinterpret_cast<const float2*>(mean)[lk];
        float2 vv = reinterpret_cast<const float2*>(var)[lk];
        float v0 = (acc0 * inv + bb.x - mm.x) * (gg.x * rsqrtf(vv.x + 1e-5f)) + tt.x;
        float v1 = (acc1 * inv + bb.y - mm.y) * (gg.y * rsqrtf(vv.y + 1e-5f)) + tt.y;
        reinterpret_cast<float2*>(hbuf + (size_t)wid * 64)[lk] =
            make_float2(fmaxf(v0, 0.f), fmaxf(v1, 0.f));
    }
}

// ---------------- output head: lane = node ----------------
__global__ __attribute__((amdgpu_waves_per_eu(4, 4))) void __launch_bounds__(256)
k_final(const float* __restrict__ hbuf, const float* __restrict__ deg,
        const float* __restrict__ inflv, const unsigned* __restrict__ scal,
        const float* __restrict__ seW1, const float* __restrict__ seb1,
        const float* __restrict__ M2, const float* __restrict__ b2f,
        const float* __restrict__ oW1,
        const float* __restrict__ oW2, const float* __restrict__ ob2,
        const float* __restrict__ oW3, const float* __restrict__ ob3,
        float* __restrict__ out, int N) {
    int tid = blockIdx.x * blockDim.x + threadIdx.x;
    int n = tid < N ? tid : N - 1;

    float degmax  = fmaxf(__uint_as_float(scal[0]), 1.0f);
    float inflmax = fmaxf(__uint_as_float(scal[1]), 1e-12f);
    float nd = deg[n] / degmax;
    float fl = inflv[n] / inflmax;

    float hid[32];
#pragma unroll
    for (int k = 0; k < 32; ++k)
        hid[k] = fmaxf(fmaf(nd, seW1[k], fmaf(fl, seW1[64 + k], seb1[k])), 0.f);

    float o1[64];
#pragma unroll
    for (int j = 0; j < 64; ++j) o1[j] = b2f[j];
#pragma unroll 4
    for (int k = 0; k < 32; ++k) {
#pragma unroll
        for (int j = 0; j < 64; ++j)
            o1[j] = fmaf(hid[k], M2[k * 64 + j], o1[j]);
    }
    const float* hr = hbuf + (size_t)n * 64;
#pragma unroll 2
    for (int c = 0; c < 16; ++c) {
        float4 hv = *reinterpret_cast<const float4*>(hr + c * 4);
        const float* wb = oW1 + c * 4 * 64;
#pragma unroll
        for (int j = 0; j < 64; ++j) {
            o1[j] = fmaf(hv.x, wb[j], o1[j]);
            o1[j] = fmaf(hv.y, wb[64 + j], o1[j]);
            o1[j] = fmaf(hv.z, wb[128 + j], o1[j]);
            o1[j] = fmaf(hv.w, wb[192 + j], o1[j]);
        }
    }
#pragma unroll
    for (int j = 0; j < 64; ++j) o1[j] = fmaxf(o1[j], 0.f);

    float o2[32];
#pragma unroll
    for (int k = 0; k < 32; ++k) o2[k] = ob2[k];
#pragma unroll 4
    for (int j = 0; j < 64; ++j) {
#pragma unroll
        for (int k = 0; k < 32; ++k)
            o2[k] = fmaf(o1[j], oW2[j * 32 + k], o2[k]);
    }
    float a0 = 0, a1 = 0, a2 = 0, a3 = 0;
#pragma unroll
    for (int k = 0; k < 32; k += 4) {
        a0 = fmaf(fmaxf(o2[k], 0.f), oW3[k], a0);
        a1 = fmaf(fmaxf(o2[k + 1], 0.f), oW3[k + 1], a1);
        a2 = fmaf(fmaxf(o2[k + 2], 0.f), oW3[k + 2], a2);
        a3 = fmaf(fmaxf(o2[k + 3], 0.f), oW3[k + 3], a3);
    }
    if (tid < N)
        out[tid] = 1.f / (1.f + __expf(-((a0 + a1) + (a2 + a3) + ob3[0])));
}

// ---------------- launch ----------------
extern "C" void kernel_launch(void* const* d_in, const int* in_sizes, int n_in,
                              void* d_out, int out_size, void* d_ws, size_t ws_size,
                              hipStream_t stream) {
    const float* x     = (const float*)d_in[0];
    const int*   ei    = (const int*)d_in[1];
    const float* faW1  = (const float*)d_in[2];
    const float* fab1  = (const float*)d_in[3];
    const float* faW2  = (const float*)d_in[4];
    const float* fab2  = (const float*)d_in[5];
    const float* projW = (const float*)d_in[6];
    const float* projb = (const float*)d_in[7];
    const float* gatW  = (const float*)d_in[8];
    const float* gatAs = (const float*)d_in[9];
    const float* gatAd = (const float*)d_in[10];
    const float* gatB  = (const float*)d_in[11];
    const float* bnG   = (const float*)d_in[12];
    const float* bnB   = (const float*)d_in[13];
    const float* bnM   = (const float*)d_in[14];
    const float* bnV   = (const float*)d_in[15];
    const float* seW1  = (const float*)d_in[16];
    const float* seb1  = (const float*)d_in[17];
    const float* seW2  = (const float*)d_in[18];
    const float* seb2  = (const float*)d_in[19];
    const float* oW1   = (const float*)d_in[20];
    const float* ob1   = (const float*)d_in[21];
    const float* oW2   = (const float*)d_in[22];
    const float* ob2   = (const float*)d_in[23];
    const float* oW3   = (const float*)d_in[24];
    const float* ob3   = (const float*)d_in[25];
    float* out = (float*)d_out;

    const int N    = in_sizes[0] / 128;
    const int E    = in_sizes[1] / 2;
    const int Etot = E + N;

    float* ws      = (float*)d_ws;
    float* hbuf    = ws;
    uint*  zbuf    = (uint*)(hbuf + (size_t)N * 64);   // N*32 uints (bf16 pairs)
    float* es      = (float*)(zbuf + (size_t)N * 64);  // region kept N*64 wide
    float* ed      = es + N;
    // ---- zero region (one memset) ----
    float* deg     = ed + N;
    float* inflsum = deg + N;
    unsigned* scal = (unsigned*)(inflsum + N);     // 8 slots
    int* cnt       = (int*)(scal + 8);
    int* cursor    = cnt + N;
    int* gcur      = cursor + N;                   // 8 slots
    // ---- end zero region ----
    int* startp    = gcur + 8;
    float* inflv   = (float*)(startp + N);
    int* esrc      = (int*)(inflv + N);            // Etot ints
    float* M2      = (float*)(esrc + Etot);        // 32*64
    float* b2f     = M2 + 32 * 64;                 // 64

    dim3 blk(256);
    int gN    = (N + 255) / 256;
    int gE    = (E + 255) / 256;
    int gM2   = (N + 127) / 128;                   // wave-split dense kernels
    int blkNW = (N * 64 + 255) / 256;              // wave-per-node (k_agg)

    hipMemsetAsync(deg, 0, ((size_t)4 * N + 16) * sizeof(float), stream);

    // stage 1: mlp(wave-split) || (deg,cnt) || prep
    k_fused1<<<gM2 + gE + 1, blk, 0, stream>>>(x, faW1, fab1, faW2, fab2, projW, projb,
                                               hbuf, N, ei, E, deg, cnt,
                                               seW2, seb2, oW1, ob1, M2, b2f, gM2, gE);
    // stage 2: CSR alloc (+self-loop)
    k_alloc<<<gN, blk, 0, stream>>>(cnt, startp, esrc, gcur, N);
    // stage 3: CSR fill + inflsum (one edge pass)
    k_fill<<<gE, blk, 0, stream>>>(ei, E, startp, cursor, esrc, deg, inflsum);

    for (int l = 0; l < 3; ++l) {
        int extra = (l == 0) ? gN : 0;             // infl/scal reduce rides on first k_z
        k_z<<<gM2 + extra, blk, 0, stream>>>(hbuf, gatW + l * 4096, gatAs + l * 64,
                                             gatAd + l * 64, zbuf, es, ed,
                                             deg, inflsum, inflv, scal, N, gM2);
        k_agg<<<blkNW, blk, 0, stream>>>(startp, cnt, esrc, es, ed, zbuf,
                                         gatB + l * 64, bnG + l * 64, bnB + l * 64,
                                         bnM + l * 64, bnV + l * 64, hbuf, N);
    }

    k_final<<<gN, blk, 0, stream>>>(hbuf, deg, inflv, scal, seW1, seb1, M2, b2f,
                                    oW1, oW2, ob2, oW3, ob3, out, N);
}

// Round 10
// 1145.537 us; speedup vs baseline: 1.2304x; 1.2304x over previous
//
#include <hip/hip_runtime.h>

// r10 = r8 revert + two safe changes (r9's LDS wave-split spilled: barrier
// forced t[64]+hp[64] live -> scratch, FETCH 63->310MB. Reverted.)
//  1. k_z: 2 threads per node split by OUTPUT half (no LDS, no barrier,
//     ~45 live regs) -> 2x occupancy, half chain length.
//  2. layer-0 z fused into fused1's MLP tail (h is thread-local there;
//     register-input GEMV, no shuffles) -> one fewer k_z, no MLP hbuf store.

typedef unsigned int uint;

__device__ __forceinline__ uint f2bf(float a) {     // RNE f32->bf16 (finite)
    uint u = __float_as_uint(a);
    return (u + 0x7fffu + ((u >> 16) & 1u)) >> 16;
}

// ---------------- fused stage 1: [MLP + z0] || deg/cnt histograms || prep ----
__global__ __attribute__((amdgpu_waves_per_eu(3, 3))) void __launch_bounds__(256)
k_fused1(const float* __restrict__ x,
         const float* __restrict__ faW1, const float* __restrict__ fab1,
         const float* __restrict__ faW2, const float* __restrict__ fab2,
         const float* __restrict__ projW, const float* __restrict__ projb,
         const float* __restrict__ W0, const float* __restrict__ as0,
         const float* __restrict__ ad0,
         uint* __restrict__ zbuf, float* __restrict__ es, float* __restrict__ ed,
         int N,
         const int* __restrict__ ei, int E,
         float* __restrict__ deg, int* __restrict__ cnt,
         const float* __restrict__ seW2, const float* __restrict__ seb2,
         const float* __restrict__ oW1, const float* __restrict__ ob1,
         float* __restrict__ M2, float* __restrict__ b2f,
         int gMlp, int gEdge) {
    int bid = blockIdx.x;
    if (bid < gMlp) {
        int tid = bid * blockDim.x + threadIdx.x;
        int n = tid < N ? tid : N - 1;
        const float* xr = x + (size_t)n * 128;

        float t[64];
#pragma unroll
        for (int j = 0; j < 64; ++j) t[j] = fab1[j];
#pragma unroll 2
        for (int c = 0; c < 32; ++c) {
            float4 xv = *reinterpret_cast<const float4*>(xr + c * 4);
            const float* wb = faW1 + c * 4 * 64;
#pragma unroll
            for (int j = 0; j < 64; ++j) {
                t[j] = fmaf(xv.x, wb[j], t[j]);
                t[j] = fmaf(xv.y, wb[64 + j], t[j]);
                t[j] = fmaf(xv.z, wb[128 + j], t[j]);
                t[j] = fmaf(xv.w, wb[192 + j], t[j]);
            }
        }
#pragma unroll
        for (int j = 0; j < 64; ++j) t[j] = fmaxf(t[j], 0.f);

        float h[64];
#pragma unroll
        for (int j = 0; j < 64; ++j) h[j] = projb[j];
#pragma unroll 2
        for (int c = 0; c < 32; ++c) {
            float4 xv = *reinterpret_cast<const float4*>(xr + c * 4);
            int i0 = c * 4;
            float f0 = fab2[i0], f1 = fab2[i0 + 1], f2 = fab2[i0 + 2], f3 = fab2[i0 + 3];
            const float* w2 = faW2 + i0;
#pragma unroll
            for (int j = 0; j < 64; ++j) {
                float tj = t[j];
                f0 = fmaf(tj, w2[j * 128], f0);
                f1 = fmaf(tj, w2[j * 128 + 1], f1);
                f2 = fmaf(tj, w2[j * 128 + 2], f2);
                f3 = fmaf(tj, w2[j * 128 + 3], f3);
            }
            float xm0 = xv.x / (1.f + __expf(-f0));
            float xm1 = xv.y / (1.f + __expf(-f1));
            float xm2 = xv.z / (1.f + __expf(-f2));
            float xm3 = xv.w / (1.f + __expf(-f3));
            const float* wp = projW + i0 * 64;
#pragma unroll
            for (int j = 0; j < 64; ++j) {
                h[j] = fmaf(xm0, wp[j], h[j]);
                h[j] = fmaf(xm1, wp[64 + j], h[j]);
                h[j] = fmaf(xm2, wp[128 + j], h[j]);
                h[j] = fmaf(xm3, wp[192 + j], h[j]);
            }
        }
        // ---- z0 = h @ W0 (register-input GEMV), es0/ed0, bf16 pack ----
        float z[64];
#pragma unroll
        for (int j = 0; j < 64; ++j) z[j] = 0.f;
#pragma unroll 2
        for (int c = 0; c < 16; ++c) {
            float h0 = h[c * 4], h1 = h[c * 4 + 1], h2 = h[c * 4 + 2], h3 = h[c * 4 + 3];
            const float* wb = W0 + c * 4 * 64;
#pragma unroll
            for (int j = 0; j < 64; ++j) {
                z[j] = fmaf(h0, wb[j], z[j]);
                z[j] = fmaf(h1, wb[64 + j], z[j]);
                z[j] = fmaf(h2, wb[128 + j], z[j]);
                z[j] = fmaf(h3, wb[192 + j], z[j]);
            }
        }
        float e0 = 0, e1 = 0, e2 = 0, e3 = 0, d0 = 0, d1 = 0, d2 = 0, d3 = 0;
#pragma unroll
        for (int j = 0; j < 64; j += 4) {
            e0 = fmaf(z[j], as0[j], e0);
            e1 = fmaf(z[j + 1], as0[j + 1], e1);
            e2 = fmaf(z[j + 2], as0[j + 2], e2);
            e3 = fmaf(z[j + 3], as0[j + 3], e3);
            d0 = fmaf(z[j], ad0[j], d0);
            d1 = fmaf(z[j + 1], ad0[j + 1], d1);
            d2 = fmaf(z[j + 2], ad0[j + 2], d2);
            d3 = fmaf(z[j + 3], ad0[j + 3], d3);
        }
        if (tid < N) {
            uint* zr = zbuf + (size_t)tid * 32;
#pragma unroll
            for (int c = 0; c < 8; ++c) {
                uint4 pv;
                pv.x = f2bf(z[c * 8 + 0]) | (f2bf(z[c * 8 + 1]) << 16);
                pv.y = f2bf(z[c * 8 + 2]) | (f2bf(z[c * 8 + 3]) << 16);
                pv.z = f2bf(z[c * 8 + 4]) | (f2bf(z[c * 8 + 5]) << 16);
                pv.w = f2bf(z[c * 8 + 6]) | (f2bf(z[c * 8 + 7]) << 16);
                *reinterpret_cast<uint4*>(zr + c * 4) = pv;
            }
            es[tid] = (e0 + e1) + (e2 + e3);
            ed[tid] = (d0 + d1) + (d2 + d3);
        }
    } else if (bid < gMlp + gEdge) {
        int e = (bid - gMlp) * blockDim.x + threadIdx.x;
        if (e < E) {
            atomicAdd(&deg[ei[e]], 1.f);
            atomicAdd(&cnt[ei[E + e]], 1);
        }
    } else {
        int tid = threadIdx.x;
        for (int o = tid; o < 32 * 64; o += 256) {
            int k = o >> 6, j = o & 63;
            float s = 0.f;
            for (int i = 0; i < 64; ++i)
                s = fmaf(seW2[k * 64 + i], oW1[(64 + i) * 64 + j], s);
            M2[o] = s;
        }
        for (int j = tid; j < 64; j += 256) {
            float s = ob1[j];
            for (int i = 0; i < 64; ++i)
                s = fmaf(seb2[i], oW1[(64 + i) * 64 + j], s);
            b2f[j] = s;
        }
    }
}

// ---------------- CSR alloc (+self-loop at slot 0) ----------------
__global__ void k_alloc(const int* __restrict__ cnt, int* __restrict__ startp,
                        int* __restrict__ esrc, int* __restrict__ gcur, int N) {
    int idx  = blockIdx.x * blockDim.x + threadIdx.x;
    int lane = threadIdx.x & 63;
    int c = idx < N ? cnt[idx] + 1 : 0;
    int sc = c;
#pragma unroll
    for (int off = 1; off < 64; off <<= 1) {
        int t = __shfl_up(sc, off, 64);
        if (lane >= off) sc += t;
    }
    int base = 0;
    if (lane == 63) base = atomicAdd(gcur, sc);
    base = __shfl(base, 63, 64);
    if (idx < N) {
        int st = base + sc - c;
        startp[idx] = st;
        esrc[st] = idx;
    }
}

// ---------------- CSR fill + inflsum (one edge pass) ----------------
__global__ void k_fill(const int* __restrict__ ei, int E,
                       const int* __restrict__ startp, int* __restrict__ cursor,
                       int* __restrict__ esrc,
                       const float* __restrict__ deg, float* __restrict__ inflsum) {
    int e = blockIdx.x * blockDim.x + threadIdx.x;
    if (e >= E) return;
    int s = ei[e], d = ei[E + e];
    int p = atomicAdd(&cursor[d], 1);
    esrc[startp[d] + 1 + p] = s;
    atomicAdd(&inflsum[s], deg[d]);
}

// ---------------- GAT z: 2 threads/node (output-half split); || infl rider ----
__global__ __attribute__((amdgpu_waves_per_eu(4, 4))) void __launch_bounds__(256)
k_z(const float* __restrict__ hbuf, const float* __restrict__ W,
    const float* __restrict__ asrc, const float* __restrict__ adst,
    uint* __restrict__ zbuf, float* __restrict__ es, float* __restrict__ ed,
    const float* __restrict__ deg, const float* __restrict__ inflsum,
    float* __restrict__ inflv, unsigned* __restrict__ scal,
    int N, int gZ) {
    int bid = blockIdx.x;
    if (bid >= gZ) {
        // structural infl + global maxes (rides on first k_z only)
        int idx = (bid - gZ) * blockDim.x + threadIdx.x;
        float dv = 0.f, iv = 0.f;
        if (idx < N) {
            dv = deg[idx];
            iv = dv > 0.f ? inflsum[idx] / dv : 0.f;
            inflv[idx] = iv;
        }
        float dm = dv, im = iv;
#pragma unroll
        for (int off = 32; off; off >>= 1) {
            dm = fmaxf(dm, __shfl_xor(dm, off, 64));
            im = fmaxf(im, __shfl_xor(im, off, 64));
        }
        if ((threadIdx.x & 63) == 0) {
            atomicMax(scal + 0, __float_as_uint(dm));
            atomicMax(scal + 1, __float_as_uint(im));
        }
        return;
    }
    int tid = bid * blockDim.x + threadIdx.x;   // 2N threads
    int pr = tid >> 1, hf = tid & 1;
    int n = pr < N ? pr : N - 1;
    const float* hr = hbuf + (size_t)n * 64;
    float z[32];
#pragma unroll
    for (int j = 0; j < 32; ++j) z[j] = 0.f;
#pragma unroll 2
    for (int c = 0; c < 16; ++c) {
        float4 hv = *reinterpret_cast<const float4*>(hr + c * 4);
        const float* wb = W + c * 4 * 64 + hf * 32;
#pragma unroll
        for (int j = 0; j < 32; ++j) {
            z[j] = fmaf(hv.x, wb[j], z[j]);
            z[j] = fmaf(hv.y, wb[64 + j], z[j]);
            z[j] = fmaf(hv.z, wb[128 + j], z[j]);
            z[j] = fmaf(hv.w, wb[192 + j], z[j]);
        }
    }
    const float* as = asrc + hf * 32;
    const float* ad = adst + hf * 32;
    float e0 = 0, e1 = 0, d0 = 0, d1 = 0;
#pragma unroll
    for (int j = 0; j < 32; j += 2) {
        e0 = fmaf(z[j], as[j], e0);
        e1 = fmaf(z[j + 1], as[j + 1], e1);
        d0 = fmaf(z[j], ad[j], d0);
        d1 = fmaf(z[j + 1], ad[j + 1], d1);
    }
    float ep = e0 + e1, dp = d0 + d1;
    ep += __shfl_xor(ep, 1, 64);   // pairs (even,odd) never straddle waves
    dp += __shfl_xor(dp, 1, 64);
    if (pr < N) {
        uint* zr = zbuf + (size_t)pr * 32 + hf * 16;
#pragma unroll
        for (int c = 0; c < 4; ++c) {
            uint4 pv;
            pv.x = f2bf(z[c * 8 + 0]) | (f2bf(z[c * 8 + 1]) << 16);
            pv.y = f2bf(z[c * 8 + 2]) | (f2bf(z[c * 8 + 3]) << 16);
            pv.z = f2bf(z[c * 8 + 4]) | (f2bf(z[c * 8 + 5]) << 16);
            pv.w = f2bf(z[c * 8 + 6]) | (f2bf(z[c * 8 + 7]) << 16);
            *reinterpret_cast<uint4*>(zr + c * 4) = pv;
        }
        if (hf == 0) { es[pr] = ep; ed[pr] = dp; }
    }
}

// ---------------- fused GAT aggregation: dual-edge half-wave (bf16 z) --------
__global__ void k_agg(const int* __restrict__ start, const int* __restrict__ cnt,
                      const int* __restrict__ esrc,
                      const float* __restrict__ es, const float* __restrict__ ed,
                      const uint* __restrict__ zb,
                      const float* __restrict__ b, const float* __restrict__ g,
                      const float* __restrict__ bta, const float* __restrict__ mean,
                      const float* __restrict__ var,
                      float* __restrict__ hbuf, int N) {
    int wid  = (blockIdx.x * blockDim.x + threadIdx.x) >> 6;
    int lane = threadIdx.x & 63;
    if (wid >= N) return;
    int row0 = start[wid];
    int c    = cnt[wid] + 1;
    float edn = ed[wid];
    int lk = lane & 31, half = lane >> 5;

    int   sreg = 0;
    float exv  = 0.f;
    if (lane < c) {
        sreg = esrc[row0 + lane];
        float e = es[sreg] + edn;
        e = e >= 0.f ? e : 0.2f * e;
        exv = __expf(e);
    }
    float ssum = exv;
    for (int k = 64 + lane; k < c; k += 64) {
        int s = esrc[row0 + k];
        float e = es[s] + edn; e = e >= 0.f ? e : 0.2f * e;
        ssum += __expf(e);
    }
#pragma unroll
    for (int off = 32; off; off >>= 1) ssum += __shfl_xor(ssum, off, 64);

    float acc0 = 0.f, acc1 = 0.f;
    int kmax = c < 64 ? c : 64;
    for (int e = half; e < kmax; e += 2) {
        int   se = __shfl(sreg, e, 64);
        float we = __shfl(exv, e, 64);
        uint p = zb[(size_t)se * 32 + lk];
        acc0 = fmaf(__uint_as_float(p << 16), we, acc0);
        acc1 = fmaf(__uint_as_float(p & 0xffff0000u), we, acc1);
    }
    for (int e = 64; e < c; ++e) {
        int s = esrc[row0 + e];
        float ee = es[s] + edn; ee = ee >= 0.f ? ee : 0.2f * ee;
        float we = __expf(ee);
        if (half == 0) {
            uint p = zb[(size_t)s * 32 + lk];
            acc0 = fmaf(__uint_as_float(p << 16), we, acc0);
            acc1 = fmaf(__uint_as_float(p & 0xffff0000u), we, acc1);
        }
    }
    acc0 += __shfl_xor(acc0, 32, 64);
    acc1 += __shfl_xor(acc1, 32, 64);

    if (half == 0) {
        float inv = 1.f / ssum;
        float2 bb = reinterpret_cast<const float2*>(b)[lk];
        float2 gg = reinterpret_cast<const float2*>(g)[lk];
        float2 tt = reinterpret_cast<const float2*>(bta)[lk];
        float2 mm = reinterpret_cast<const float2*>(mean)[lk];
        float2 vv = reinterpret_cast<const float2*>(var)[lk];
        float v0 = (acc0 * inv + bb.x - mm.x) * (gg.x * rsqrtf(vv.x + 1e-5f)) + tt.x;
        float v1 = (acc1 * inv + bb.y - mm.y) * (gg.y * rsqrtf(vv.y + 1e-5f)) + tt.y;
        reinterpret_cast<float2*>(hbuf + (size_t)wid * 64)[lk] =
            make_float2(fmaxf(v0, 0.f), fmaxf(v1, 0.f));
    }
}

// ---------------- output head: lane = node ----------------
__global__ __attribute__((amdgpu_waves_per_eu(4, 4))) void __launch_bounds__(256)
k_final(const float* __restrict__ hbuf, const float* __restrict__ deg,
        const float* __restrict__ inflv, const unsigned* __restrict__ scal,
        const float* __restrict__ seW1, const float* __restrict__ seb1,
        const float* __restrict__ M2, const float* __restrict__ b2f,
        const float* __restrict__ oW1,
        const float* __restrict__ oW2, const float* __restrict__ ob2,
        const float* __restrict__ oW3, const float* __restrict__ ob3,
        float* __restrict__ out, int N) {
    int tid = blockIdx.x * blockDim.x + threadIdx.x;
    int n = tid < N ? tid : N - 1;

    float degmax  = fmaxf(__uint_as_float(scal[0]), 1.0f);
    float inflmax = fmaxf(__uint_as_float(scal[1]), 1e-12f);
    float nd = deg[n] / degmax;
    float fl = inflv[n] / inflmax;

    float hid[32];
#pragma unroll
    for (int k = 0; k < 32; ++k)
        hid[k] = fmaxf(fmaf(nd, seW1[k], fmaf(fl, seW1[64 + k], seb1[k])), 0.f);

    float o1[64];
#pragma unroll
    for (int j = 0; j < 64; ++j) o1[j] = b2f[j];
#pragma unroll 4
    for (int k = 0; k < 32; ++k) {
#pragma unroll
        for (int j = 0; j < 64; ++j)
            o1[j] = fmaf(hid[k], M2[k * 64 + j], o1[j]);
    }
    const float* hr = hbuf + (size_t)n * 64;
#pragma unroll 2
    for (int c = 0; c < 16; ++c) {
        float4 hv = *reinterpret_cast<const float4*>(hr + c * 4);
        const float* wb = oW1 + c * 4 * 64;
#pragma unroll
        for (int j = 0; j < 64; ++j) {
            o1[j] = fmaf(hv.x, wb[j], o1[j]);
            o1[j] = fmaf(hv.y, wb[64 + j], o1[j]);
            o1[j] = fmaf(hv.z, wb[128 + j], o1[j]);
            o1[j] = fmaf(hv.w, wb[192 + j], o1[j]);
        }
    }
#pragma unroll
    for (int j = 0; j < 64; ++j) o1[j] = fmaxf(o1[j], 0.f);

    float o2[32];
#pragma unroll
    for (int k = 0; k < 32; ++k) o2[k] = ob2[k];
#pragma unroll 4
    for (int j = 0; j < 64; ++j) {
#pragma unroll
        for (int k = 0; k < 32; ++k)
            o2[k] = fmaf(o1[j], oW2[j * 32 + k], o2[k]);
    }
    float a0 = 0, a1 = 0, a2 = 0, a3 = 0;
#pragma unroll
    for (int k = 0; k < 32; k += 4) {
        a0 = fmaf(fmaxf(o2[k], 0.f), oW3[k], a0);
        a1 = fmaf(fmaxf(o2[k + 1], 0.f), oW3[k + 1], a1);
        a2 = fmaf(fmaxf(o2[k + 2], 0.f), oW3[k + 2], a2);
        a3 = fmaf(fmaxf(o2[k + 3], 0.f), oW3[k + 3], a3);
    }
    if (tid < N)
        out[tid] = 1.f / (1.f + __expf(-((a0 + a1) + (a2 + a3) + ob3[0])));
}

// ---------------- launch ----------------
extern "C" void kernel_launch(void* const* d_in, const int* in_sizes, int n_in,
                              void* d_out, int out_size, void* d_ws, size_t ws_size,
                              hipStream_t stream) {
    const float* x     = (const float*)d_in[0];
    const int*   ei    = (const int*)d_in[1];
    const float* faW1  = (const float*)d_in[2];
    const float* fab1  = (const float*)d_in[3];
    const float* faW2  = (const float*)d_in[4];
    const float* fab2  = (const float*)d_in[5];
    const float* projW = (const float*)d_in[6];
    const float* projb = (const float*)d_in[7];
    const float* gatW  = (const float*)d_in[8];
    const float* gatAs = (const float*)d_in[9];
    const float* gatAd = (const float*)d_in[10];
    const float* gatB  = (const float*)d_in[11];
    const float* bnG   = (const float*)d_in[12];
    const float* bnB   = (const float*)d_in[13];
    const float* bnM   = (const float*)d_in[14];
    const float* bnV   = (const float*)d_in[15];
    const float* seW1  = (const float*)d_in[16];
    const float* seb1  = (const float*)d_in[17];
    const float* seW2  = (const float*)d_in[18];
    const float* seb2  = (const float*)d_in[19];
    const float* oW1   = (const float*)d_in[20];
    const float* ob1   = (const float*)d_in[21];
    const float* oW2   = (const float*)d_in[22];
    const float* ob2   = (const float*)d_in[23];
    const float* oW3   = (const float*)d_in[24];
    const float* ob3   = (const float*)d_in[25];
    float* out = (float*)d_out;

    const int N    = in_sizes[0] / 128;
    const int E    = in_sizes[1] / 2;
    const int Etot = E + N;

    float* ws      = (float*)d_ws;
    float* hbuf    = ws;
    uint*  zbuf    = (uint*)(hbuf + (size_t)N * 64);   // N*32 uints (bf16 pairs)
    float* es      = (float*)(zbuf + (size_t)N * 64);  // region kept N*64 wide
    float* ed      = es + N;
    // ---- zero region (one memset) ----
    float* deg     = ed + N;
    float* inflsum = deg + N;
    unsigned* scal = (unsigned*)(inflsum + N);     // 8 slots
    int* cnt       = (int*)(scal + 8);
    int* cursor    = cnt + N;
    int* gcur      = cursor + N;                   // 8 slots
    // ---- end zero region ----
    int* startp    = gcur + 8;
    float* inflv   = (float*)(startp + N);
    int* esrc      = (int*)(inflv + N);            // Etot ints
    float* M2      = (float*)(esrc + Etot);        // 32*64
    float* b2f     = M2 + 32 * 64;                 // 64

    dim3 blk(256);
    int gN    = (N + 255) / 256;
    int gE    = (E + 255) / 256;
    int gZ2   = (2 * N + 255) / 256;               // 2 threads/node k_z
    int blkNW = (N * 64 + 255) / 256;              // wave-per-node (k_agg)

    hipMemsetAsync(deg, 0, ((size_t)4 * N + 16) * sizeof(float), stream);

    // stage 1: [mlp+z0] || (deg,cnt) || prep
    k_fused1<<<gN + gE + 1, blk, 0, stream>>>(x, faW1, fab1, faW2, fab2, projW, projb,
                                              gatW, gatAs, gatAd, zbuf, es, ed,
                                              hbuf == nullptr ? 0 : N, ei, E, deg, cnt,
                                              seW2, seb2, oW1, ob1, M2, b2f, gN, gE);
    // stage 2: CSR alloc (+self-loop)
    k_alloc<<<gN, blk, 0, stream>>>(cnt, startp, esrc, gcur, N);
    // stage 3: CSR fill + inflsum (one edge pass)
    k_fill<<<gE, blk, 0, stream>>>(ei, E, startp, cursor, esrc, deg, inflsum);

    for (int l = 0; l < 3; ++l) {
        k_agg<<<blkNW, blk, 0, stream>>>(startp, cnt, esrc, es, ed, zbuf,
                                         gatB + l * 64, bnG + l * 64, bnB + l * 64,
                                         bnM + l * 64, bnV + l * 64, hbuf, N);
        if (l < 2) {
            int extra = (l == 0) ? gN : 0;         // infl/scal rider on first k_z
            k_z<<<gZ2 + extra, blk, 0, stream>>>(hbuf, gatW + (l + 1) * 4096,
                                                 gatAs + (l + 1) * 64, gatAd + (l + 1) * 64,
                                                 zbuf, es, ed,
                                                 deg, inflsum, inflv, scal, N, gZ2);
        }
    }

    k_final<<<gN, blk, 0, stream>>>(hbuf, deg, inflv, scal, seW1, seb1, M2, b2f,
                                    oW1, oW2, ob2, oW3, ob3, out, N);
}

// Round 11
// 1127.090 us; speedup vs baseline: 1.2505x; 1.0164x over previous
//
#include <hip/hip_runtime.h>

// r11 = r8 fused1 (proven no-spill) + r10's k_z output-half split kept for
// all 3 layers. r10 post-mortem: fusing z0 into the MLP made h[64]+z[64]
// live simultaneously -> spill (WRITE 640-760MB). Two 64-float register
// arrays live at once is this kernel family's spill threshold; don't cross.

typedef unsigned int uint;

__device__ __forceinline__ uint f2bf(float a) {     // RNE f32->bf16 (finite)
    uint u = __float_as_uint(a);
    return (u + 0x7fffu + ((u >> 16) & 1u)) >> 16;
}

// ---------------- fused stage 1: node MLP || deg/cnt histograms || prep ------
__global__ __attribute__((amdgpu_waves_per_eu(3, 3))) void __launch_bounds__(256)
k_fused1(const float* __restrict__ x,
         const float* __restrict__ faW1, const float* __restrict__ fab1,
         const float* __restrict__ faW2, const float* __restrict__ fab2,
         const float* __restrict__ projW, const float* __restrict__ projb,
         float* __restrict__ hbuf, int N,
         const int* __restrict__ ei, int E,
         float* __restrict__ deg, int* __restrict__ cnt,
         const float* __restrict__ seW2, const float* __restrict__ seb2,
         const float* __restrict__ oW1, const float* __restrict__ ob1,
         float* __restrict__ M2, float* __restrict__ b2f,
         int gMlp, int gEdge) {
    int bid = blockIdx.x;
    if (bid < gMlp) {
        int tid = bid * blockDim.x + threadIdx.x;
        int n = tid < N ? tid : N - 1;
        const float* xr = x + (size_t)n * 128;

        float t[64];
#pragma unroll
        for (int j = 0; j < 64; ++j) t[j] = fab1[j];
#pragma unroll 2
        for (int c = 0; c < 32; ++c) {
            float4 xv = *reinterpret_cast<const float4*>(xr + c * 4);
            const float* wb = faW1 + c * 4 * 64;
#pragma unroll
            for (int j = 0; j < 64; ++j) {
                t[j] = fmaf(xv.x, wb[j], t[j]);
                t[j] = fmaf(xv.y, wb[64 + j], t[j]);
                t[j] = fmaf(xv.z, wb[128 + j], t[j]);
                t[j] = fmaf(xv.w, wb[192 + j], t[j]);
            }
        }
#pragma unroll
        for (int j = 0; j < 64; ++j) t[j] = fmaxf(t[j], 0.f);

        float h[64];
#pragma unroll
        for (int j = 0; j < 64; ++j) h[j] = projb[j];
#pragma unroll 2
        for (int c = 0; c < 32; ++c) {
            float4 xv = *reinterpret_cast<const float4*>(xr + c * 4);
            int i0 = c * 4;
            float f0 = fab2[i0], f1 = fab2[i0 + 1], f2 = fab2[i0 + 2], f3 = fab2[i0 + 3];
            const float* w2 = faW2 + i0;
#pragma unroll
            for (int j = 0; j < 64; ++j) {
                float tj = t[j];
                f0 = fmaf(tj, w2[j * 128], f0);
                f1 = fmaf(tj, w2[j * 128 + 1], f1);
                f2 = fmaf(tj, w2[j * 128 + 2], f2);
                f3 = fmaf(tj, w2[j * 128 + 3], f3);
            }
            float xm0 = xv.x / (1.f + __expf(-f0));
            float xm1 = xv.y / (1.f + __expf(-f1));
            float xm2 = xv.z / (1.f + __expf(-f2));
            float xm3 = xv.w / (1.f + __expf(-f3));
            const float* wp = projW + i0 * 64;
#pragma unroll
            for (int j = 0; j < 64; ++j) {
                h[j] = fmaf(xm0, wp[j], h[j]);
                h[j] = fmaf(xm1, wp[64 + j], h[j]);
                h[j] = fmaf(xm2, wp[128 + j], h[j]);
                h[j] = fmaf(xm3, wp[192 + j], h[j]);
            }
        }
        if (tid < N) {
            float* hr = hbuf + (size_t)tid * 64;
#pragma unroll
            for (int c = 0; c < 16; ++c)
                *reinterpret_cast<float4*>(hr + c * 4) =
                    make_float4(h[c * 4], h[c * 4 + 1], h[c * 4 + 2], h[c * 4 + 3]);
        }
    } else if (bid < gMlp + gEdge) {
        int e = (bid - gMlp) * blockDim.x + threadIdx.x;
        if (e < E) {
            atomicAdd(&deg[ei[e]], 1.f);
            atomicAdd(&cnt[ei[E + e]], 1);
        }
    } else {
        int tid = threadIdx.x;
        for (int o = tid; o < 32 * 64; o += 256) {
            int k = o >> 6, j = o & 63;
            float s = 0.f;
            for (int i = 0; i < 64; ++i)
                s = fmaf(seW2[k * 64 + i], oW1[(64 + i) * 64 + j], s);
            M2[o] = s;
        }
        for (int j = tid; j < 64; j += 256) {
            float s = ob1[j];
            for (int i = 0; i < 64; ++i)
                s = fmaf(seb2[i], oW1[(64 + i) * 64 + j], s);
            b2f[j] = s;
        }
    }
}

// ---------------- CSR alloc (+self-loop at slot 0) ----------------
__global__ void k_alloc(const int* __restrict__ cnt, int* __restrict__ startp,
                        int* __restrict__ esrc, int* __restrict__ gcur, int N) {
    int idx  = blockIdx.x * blockDim.x + threadIdx.x;
    int lane = threadIdx.x & 63;
    int c = idx < N ? cnt[idx] + 1 : 0;
    int sc = c;
#pragma unroll
    for (int off = 1; off < 64; off <<= 1) {
        int t = __shfl_up(sc, off, 64);
        if (lane >= off) sc += t;
    }
    int base = 0;
    if (lane == 63) base = atomicAdd(gcur, sc);
    base = __shfl(base, 63, 64);
    if (idx < N) {
        int st = base + sc - c;
        startp[idx] = st;
        esrc[st] = idx;
    }
}

// ---------------- CSR fill + inflsum (one edge pass) ----------------
__global__ void k_fill(const int* __restrict__ ei, int E,
                       const int* __restrict__ startp, int* __restrict__ cursor,
                       int* __restrict__ esrc,
                       const float* __restrict__ deg, float* __restrict__ inflsum) {
    int e = blockIdx.x * blockDim.x + threadIdx.x;
    if (e >= E) return;
    int s = ei[e], d = ei[E + e];
    int p = atomicAdd(&cursor[d], 1);
    esrc[startp[d] + 1 + p] = s;
    atomicAdd(&inflsum[s], deg[d]);
}

// ---------------- GAT z: 2 threads/node (output-half split); || infl rider ----
__global__ __attribute__((amdgpu_waves_per_eu(4, 4))) void __launch_bounds__(256)
k_z(const float* __restrict__ hbuf, const float* __restrict__ W,
    const float* __restrict__ asrc, const float* __restrict__ adst,
    uint* __restrict__ zbuf, float* __restrict__ es, float* __restrict__ ed,
    const float* __restrict__ deg, const float* __restrict__ inflsum,
    float* __restrict__ inflv, unsigned* __restrict__ scal,
    int N, int gZ) {
    int bid = blockIdx.x;
    if (bid >= gZ) {
        // structural infl + global maxes (rides on first k_z only)
        int idx = (bid - gZ) * blockDim.x + threadIdx.x;
        float dv = 0.f, iv = 0.f;
        if (idx < N) {
            dv = deg[idx];
            iv = dv > 0.f ? inflsum[idx] / dv : 0.f;
            inflv[idx] = iv;
        }
        float dm = dv, im = iv;
#pragma unroll
        for (int off = 32; off; off >>= 1) {
            dm = fmaxf(dm, __shfl_xor(dm, off, 64));
            im = fmaxf(im, __shfl_xor(im, off, 64));
        }
        if ((threadIdx.x & 63) == 0) {
            atomicMax(scal + 0, __float_as_uint(dm));
            atomicMax(scal + 1, __float_as_uint(im));
        }
        return;
    }
    int tid = bid * blockDim.x + threadIdx.x;   // 2N threads
    int pr = tid >> 1, hf = tid & 1;
    int n = pr < N ? pr : N - 1;
    const float* hr = hbuf + (size_t)n * 64;
    float z[32];
#pragma unroll
    for (int j = 0; j < 32; ++j) z[j] = 0.f;
#pragma unroll 2
    for (int c = 0; c < 16; ++c) {
        float4 hv = *reinterpret_cast<const float4*>(hr + c * 4);
        const float* wb = W + c * 4 * 64 + hf * 32;
#pragma unroll
        for (int j = 0; j < 32; ++j) {
            z[j] = fmaf(hv.x, wb[j], z[j]);
            z[j] = fmaf(hv.y, wb[64 + j], z[j]);
            z[j] = fmaf(hv.z, wb[128 + j], z[j]);
            z[j] = fmaf(hv.w, wb[192 + j], z[j]);
        }
    }
    const float* as = asrc + hf * 32;
    const float* ad = adst + hf * 32;
    float e0 = 0, e1 = 0, d0 = 0, d1 = 0;
#pragma unroll
    for (int j = 0; j < 32; j += 2) {
        e0 = fmaf(z[j], as[j], e0);
        e1 = fmaf(z[j + 1], as[j + 1], e1);
        d0 = fmaf(z[j], ad[j], d0);
        d1 = fmaf(z[j + 1], ad[j + 1], d1);
    }
    float ep = e0 + e1, dp = d0 + d1;
    ep += __shfl_xor(ep, 1, 64);   // pairs (even,odd) never straddle waves
    dp += __shfl_xor(dp, 1, 64);
    if (pr < N) {
        uint* zr = zbuf + (size_t)pr * 32 + hf * 16;
#pragma unroll
        for (int c = 0; c < 4; ++c) {
            uint4 pv;
            pv.x = f2bf(z[c * 8 + 0]) | (f2bf(z[c * 8 + 1]) << 16);
            pv.y = f2bf(z[c * 8 + 2]) | (f2bf(z[c * 8 + 3]) << 16);
            pv.z = f2bf(z[c * 8 + 4]) | (f2bf(z[c * 8 + 5]) << 16);
            pv.w = f2bf(z[c * 8 + 6]) | (f2bf(z[c * 8 + 7]) << 16);
            *reinterpret_cast<uint4*>(zr + c * 4) = pv;
        }
        if (hf == 0) { es[pr] = ep; ed[pr] = dp; }
    }
}

// ---------------- fused GAT aggregation: dual-edge half-wave (bf16 z) --------
__global__ void k_agg(const int* __restrict__ start, const int* __restrict__ cnt,
                      const int* __restrict__ esrc,
                      const float* __restrict__ es, const float* __restrict__ ed,
                      const uint* __restrict__ zb,
                      const float* __restrict__ b, const float* __restrict__ g,
                      const float* __restrict__ bta, const float* __restrict__ mean,
                      const float* __restrict__ var,
                      float* __restrict__ hbuf, int N) {
    int wid  = (blockIdx.x * blockDim.x + threadIdx.x) >> 6;
    int lane = threadIdx.x & 63;
    if (wid >= N) return;
    int row0 = start[wid];
    int c    = cnt[wid] + 1;
    float edn = ed[wid];
    int lk = lane & 31, half = lane >> 5;

    int   sreg = 0;
    float exv  = 0.f;
    if (lane < c) {
        sreg = esrc[row0 + lane];
        float e = es[sreg] + edn;
        e = e >= 0.f ? e : 0.2f * e;
        exv = __expf(e);
    }
    float ssum = exv;
    for (int k = 64 + lane; k < c; k += 64) {
        int s = esrc[row0 + k];
        float e = es[s] + edn; e = e >= 0.f ? e : 0.2f * e;
        ssum += __expf(e);
    }
#pragma unroll
    for (int off = 32; off; off >>= 1) ssum += __shfl_xor(ssum, off, 64);

    float acc0 = 0.f, acc1 = 0.f;
    int kmax = c < 64 ? c : 64;
    for (int e = half; e < kmax; e += 2) {
        int   se = __shfl(sreg, e, 64);
        float we = __shfl(exv, e, 64);
        uint p = zb[(size_t)se * 32 + lk];
        acc0 = fmaf(__uint_as_float(p << 16), we, acc0);
        acc1 = fmaf(__uint_as_float(p & 0xffff0000u), we, acc1);
    }
    for (int e = 64; e < c; ++e) {
        int s = esrc[row0 + e];
        float ee = es[s] + edn; ee = ee >= 0.f ? ee : 0.2f * ee;
        float we = __expf(ee);
        if (half == 0) {
            uint p = zb[(size_t)s * 32 + lk];
            acc0 = fmaf(__uint_as_float(p << 16), we, acc0);
            acc1 = fmaf(__uint_as_float(p & 0xffff0000u), we, acc1);
        }
    }
    acc0 += __shfl_xor(acc0, 32, 64);
    acc1 += __shfl_xor(acc1, 32, 64);

    if (half == 0) {
        float inv = 1.f / ssum;
        float2 bb = reinterpret_cast<const float2*>(b)[lk];
        float2 gg = reinterpret_cast<const float2*>(g)[lk];
        float2 tt = reinterpret_cast<const float2*>(bta)[lk];
        float2 mm = reinterpret_cast<const float2*>(mean)[lk];
        float2 vv = reinterpret_cast<const float2*>(var)[lk];
        float v0 = (acc0 * inv + bb.x - mm.x) * (gg.x * rsqrtf(vv.x + 1e-5f)) + tt.x;
        float v1 = (acc1 * inv + bb.y - mm.y) * (gg.y * rsqrtf(vv.y + 1e-5f)) + tt.y;
        reinterpret_cast<float2*>(hbuf + (size_t)wid * 64)[lk] =
            make_float2(fmaxf(v0, 0.f), fmaxf(v1, 0.f));
    }
}

// ---------------- output head: lane = node ----------------
__global__ __attribute__((amdgpu_waves_per_eu(4, 4))) void __launch_bounds__(256)
k_final(const float* __restrict__ hbuf, const float* __restrict__ deg,
        const float* __restrict__ inflv, const unsigned* __restrict__ scal,
        const float* __restrict__ seW1, const float* __restrict__ seb1,
        const float* __restrict__ M2, const float* __restrict__ b2f,
        const float* __restrict__ oW1,
        const float* __restrict__ oW2, const float* __restrict__ ob2,
        const float* __restrict__ oW3, const float* __restrict__ ob3,
        float* __restrict__ out, int N) {
    int tid = blockIdx.x * blockDim.x + threadIdx.x;
    int n = tid < N ? tid : N - 1;

    float degmax  = fmaxf(__uint_as_float(scal[0]), 1.0f);
    float inflmax = fmaxf(__uint_as_float(scal[1]), 1e-12f);
    float nd = deg[n] / degmax;
    float fl = inflv[n] / inflmax;

    float hid[32];
#pragma unroll
    for (int k = 0; k < 32; ++k)
        hid[k] = fmaxf(fmaf(nd, seW1[k], fmaf(fl, seW1[64 + k], seb1[k])), 0.f);

    float o1[64];
#pragma unroll
    for (int j = 0; j < 64; ++j) o1[j] = b2f[j];
#pragma unroll 4
    for (int k = 0; k < 32; ++k) {
#pragma unroll
        for (int j = 0; j < 64; ++j)
            o1[j] = fmaf(hid[k], M2[k * 64 + j], o1[j]);
    }
    const float* hr = hbuf + (size_t)n * 64;
#pragma unroll 2
    for (int c = 0; c < 16; ++c) {
        float4 hv = *reinterpret_cast<const float4*>(hr + c * 4);
        const float* wb = oW1 + c * 4 * 64;
#pragma unroll
        for (int j = 0; j < 64; ++j) {
            o1[j] = fmaf(hv.x, wb[j], o1[j]);
            o1[j] = fmaf(hv.y, wb[64 + j], o1[j]);
            o1[j] = fmaf(hv.z, wb[128 + j], o1[j]);
            o1[j] = fmaf(hv.w, wb[192 + j], o1[j]);
        }
    }
#pragma unroll
    for (int j = 0; j < 64; ++j) o1[j] = fmaxf(o1[j], 0.f);

    float o2[32];
#pragma unroll
    for (int k = 0; k < 32; ++k) o2[k] = ob2[k];
#pragma unroll 4
    for (int j = 0; j < 64; ++j) {
#pragma unroll
        for (int k = 0; k < 32; ++k)
            o2[k] = fmaf(o1[j], oW2[j * 32 + k], o2[k]);
    }
    float a0 = 0, a1 = 0, a2 = 0, a3 = 0;
#pragma unroll
    for (int k = 0; k < 32; k += 4) {
        a0 = fmaf(fmaxf(o2[k], 0.f), oW3[k], a0);
        a1 = fmaf(fmaxf(o2[k + 1], 0.f), oW3[k + 1], a1);
        a2 = fmaf(fmaxf(o2[k + 2], 0.f), oW3[k + 2], a2);
        a3 = fmaf(fmaxf(o2[k + 3], 0.f), oW3[k + 3], a3);
    }
    if (tid < N)
        out[tid] = 1.f / (1.f + __expf(-((a0 + a1) + (a2 + a3) + ob3[0])));
}

// ---------------- launch ----------------
extern "C" void kernel_launch(void* const* d_in, const int* in_sizes, int n_in,
                              void* d_out, int out_size, void* d_ws, size_t ws_size,
                              hipStream_t stream) {
    const float* x     = (const float*)d_in[0];
    const int*   ei    = (const int*)d_in[1];
    const float* faW1  = (const float*)d_in[2];
    const float* fab1  = (const float*)d_in[3];
    const float* faW2  = (const float*)d_in[4];
    const float* fab2  = (const float*)d_in[5];
    const float* projW = (const float*)d_in[6];
    const float* projb = (const float*)d_in[7];
    const float* gatW  = (const float*)d_in[8];
    const float* gatAs = (const float*)d_in[9];
    const float* gatAd = (const float*)d_in[10];
    const float* gatB  = (const float*)d_in[11];
    const float* bnG   = (const float*)d_in[12];
    const float* bnB   = (const float*)d_in[13];
    const float* bnM   = (const float*)d_in[14];
    const float* bnV   = (const float*)d_in[15];
    const float* seW1  = (const float*)d_in[16];
    const float* seb1  = (const float*)d_in[17];
    const float* seW2  = (const float*)d_in[18];
    const float* seb2  = (const float*)d_in[19];
    const float* oW1   = (const float*)d_in[20];
    const float* ob1   = (const float*)d_in[21];
    const float* oW2   = (const float*)d_in[22];
    const float* ob2   = (const float*)d_in[23];
    const float* oW3   = (const float*)d_in[24];
    const float* ob3   = (const float*)d_in[25];
    float* out = (float*)d_out;

    const int N    = in_sizes[0] / 128;
    const int E    = in_sizes[1] / 2;
    const int Etot = E + N;

    float* ws      = (float*)d_ws;
    float* hbuf    = ws;
    uint*  zbuf    = (uint*)(hbuf + (size_t)N * 64);   // N*32 uints (bf16 pairs)
    float* es      = (float*)(zbuf + (size_t)N * 64);
    float* ed      = es + N;
    // ---- zero region (one memset) ----
    float* deg     = ed + N;
    float* inflsum = deg + N;
    unsigned* scal = (unsigned*)(inflsum + N);     // 8 slots
    int* cnt       = (int*)(scal + 8);
    int* cursor    = cnt + N;
    int* gcur      = cursor + N;                   // 8 slots
    // ---- end zero region ----
    int* startp    = gcur + 8;
    float* inflv   = (float*)(startp + N);
    int* esrc      = (int*)(inflv + N);            // Etot ints
    float* M2      = (float*)(esrc + Etot);        // 32*64
    float* b2f     = M2 + 32 * 64;                 // 64

    dim3 blk(256);
    int gN    = (N + 255) / 256;
    int gE    = (E + 255) / 256;
    int gZ2   = (2 * N + 255) / 256;               // 2 threads/node k_z
    int blkNW = (N * 64 + 255) / 256;              // wave-per-node (k_agg)

    hipMemsetAsync(deg, 0, ((size_t)4 * N + 16) * sizeof(float), stream);

    // stage 1: mlp || (deg,cnt) || prep
    k_fused1<<<gN + gE + 1, blk, 0, stream>>>(x, faW1, fab1, faW2, fab2, projW, projb,
                                              hbuf, N, ei, E, deg, cnt,
                                              seW2, seb2, oW1, ob1, M2, b2f, gN, gE);
    // stage 2: CSR alloc (+self-loop)
    k_alloc<<<gN, blk, 0, stream>>>(cnt, startp, esrc, gcur, N);
    // stage 3: CSR fill + inflsum (one edge pass)
    k_fill<<<gE, blk, 0, stream>>>(ei, E, startp, cursor, esrc, deg, inflsum);

    for (int l = 0; l < 3; ++l) {
        int extra = (l == 0) ? gN : 0;             // infl/scal rider on first k_z
        k_z<<<gZ2 + extra, blk, 0, stream>>>(hbuf, gatW + l * 4096, gatAs + l * 64,
                                             gatAd + l * 64, zbuf, es, ed,
                                             deg, inflsum, inflv, scal, N, gZ2);
        k_agg<<<blkNW, blk, 0, stream>>>(startp, cnt, esrc, es, ed, zbuf,
                                         gatB + l * 64, bnG + l * 64, bnB + l * 64,
                                         bnM + l * 64, bnV + l * 64, hbuf, N);
    }

    k_final<<<gN, blk, 0, stream>>>(hbuf, deg, inflv, scal, seW1, seb1, M2, b2f,
                                    oW1, oW2, ob2, oW3, ob3, out, N);
}

// Round 12
// 840.073 us; speedup vs baseline: 1.6778x; 1.3417x over previous
//
#include <hip/hip_runtime.h>

// r12 = r11 with (a) k_z reverted to r8 lane-per-node (r11's per-thread
// output split broke wave-uniform weight addressing -> vector weight loads,
// +80us/layer), and (b) k_agg upgraded to quad-edge quarter-wave: 16 lanes
// x uint2 (4 bf16) per edge -> one gather instruction serves 4 edges in
// flight (2x MLP vs dual-edge), same bytes.

typedef unsigned int uint;

__device__ __forceinline__ uint f2bf(float a) {     // RNE f32->bf16 (finite)
    uint u = __float_as_uint(a);
    return (u + 0x7fffu + ((u >> 16) & 1u)) >> 16;
}
__device__ __forceinline__ float bflo(uint p) { return __uint_as_float(p << 16); }
__device__ __forceinline__ float bfhi(uint p) { return __uint_as_float(p & 0xffff0000u); }

// ---------------- fused stage 1: node MLP || deg/cnt histograms || prep ------
__global__ __attribute__((amdgpu_waves_per_eu(3, 3))) void __launch_bounds__(256)
k_fused1(const float* __restrict__ x,
         const float* __restrict__ faW1, const float* __restrict__ fab1,
         const float* __restrict__ faW2, const float* __restrict__ fab2,
         const float* __restrict__ projW, const float* __restrict__ projb,
         float* __restrict__ hbuf, int N,
         const int* __restrict__ ei, int E,
         float* __restrict__ deg, int* __restrict__ cnt,
         const float* __restrict__ seW2, const float* __restrict__ seb2,
         const float* __restrict__ oW1, const float* __restrict__ ob1,
         float* __restrict__ M2, float* __restrict__ b2f,
         int gMlp, int gEdge) {
    int bid = blockIdx.x;
    if (bid < gMlp) {
        int tid = bid * blockDim.x + threadIdx.x;
        int n = tid < N ? tid : N - 1;
        const float* xr = x + (size_t)n * 128;

        float t[64];
#pragma unroll
        for (int j = 0; j < 64; ++j) t[j] = fab1[j];
#pragma unroll 2
        for (int c = 0; c < 32; ++c) {
            float4 xv = *reinterpret_cast<const float4*>(xr + c * 4);
            const float* wb = faW1 + c * 4 * 64;
#pragma unroll
            for (int j = 0; j < 64; ++j) {
                t[j] = fmaf(xv.x, wb[j], t[j]);
                t[j] = fmaf(xv.y, wb[64 + j], t[j]);
                t[j] = fmaf(xv.z, wb[128 + j], t[j]);
                t[j] = fmaf(xv.w, wb[192 + j], t[j]);
            }
        }
#pragma unroll
        for (int j = 0; j < 64; ++j) t[j] = fmaxf(t[j], 0.f);

        float h[64];
#pragma unroll
        for (int j = 0; j < 64; ++j) h[j] = projb[j];
#pragma unroll 2
        for (int c = 0; c < 32; ++c) {
            float4 xv = *reinterpret_cast<const float4*>(xr + c * 4);
            int i0 = c * 4;
            float f0 = fab2[i0], f1 = fab2[i0 + 1], f2 = fab2[i0 + 2], f3 = fab2[i0 + 3];
            const float* w2 = faW2 + i0;
#pragma unroll
            for (int j = 0; j < 64; ++j) {
                float tj = t[j];
                f0 = fmaf(tj, w2[j * 128], f0);
                f1 = fmaf(tj, w2[j * 128 + 1], f1);
                f2 = fmaf(tj, w2[j * 128 + 2], f2);
                f3 = fmaf(tj, w2[j * 128 + 3], f3);
            }
            float xm0 = xv.x / (1.f + __expf(-f0));
            float xm1 = xv.y / (1.f + __expf(-f1));
            float xm2 = xv.z / (1.f + __expf(-f2));
            float xm3 = xv.w / (1.f + __expf(-f3));
            const float* wp = projW + i0 * 64;
#pragma unroll
            for (int j = 0; j < 64; ++j) {
                h[j] = fmaf(xm0, wp[j], h[j]);
                h[j] = fmaf(xm1, wp[64 + j], h[j]);
                h[j] = fmaf(xm2, wp[128 + j], h[j]);
                h[j] = fmaf(xm3, wp[192 + j], h[j]);
            }
        }
        if (tid < N) {
            float* hr = hbuf + (size_t)tid * 64;
#pragma unroll
            for (int c = 0; c < 16; ++c)
                *reinterpret_cast<float4*>(hr + c * 4) =
                    make_float4(h[c * 4], h[c * 4 + 1], h[c * 4 + 2], h[c * 4 + 3]);
        }
    } else if (bid < gMlp + gEdge) {
        int e = (bid - gMlp) * blockDim.x + threadIdx.x;
        if (e < E) {
            atomicAdd(&deg[ei[e]], 1.f);
            atomicAdd(&cnt[ei[E + e]], 1);
        }
    } else {
        int tid = threadIdx.x;
        for (int o = tid; o < 32 * 64; o += 256) {
            int k = o >> 6, j = o & 63;
            float s = 0.f;
            for (int i = 0; i < 64; ++i)
                s = fmaf(seW2[k * 64 + i], oW1[(64 + i) * 64 + j], s);
            M2[o] = s;
        }
        for (int j = tid; j < 64; j += 256) {
            float s = ob1[j];
            for (int i = 0; i < 64; ++i)
                s = fmaf(seb2[i], oW1[(64 + i) * 64 + j], s);
            b2f[j] = s;
        }
    }
}

// ---------------- CSR alloc (+self-loop at slot 0) ----------------
__global__ void k_alloc(const int* __restrict__ cnt, int* __restrict__ startp,
                        int* __restrict__ esrc, int* __restrict__ gcur, int N) {
    int idx  = blockIdx.x * blockDim.x + threadIdx.x;
    int lane = threadIdx.x & 63;
    int c = idx < N ? cnt[idx] + 1 : 0;
    int sc = c;
#pragma unroll
    for (int off = 1; off < 64; off <<= 1) {
        int t = __shfl_up(sc, off, 64);
        if (lane >= off) sc += t;
    }
    int base = 0;
    if (lane == 63) base = atomicAdd(gcur, sc);
    base = __shfl(base, 63, 64);
    if (idx < N) {
        int st = base + sc - c;
        startp[idx] = st;
        esrc[st] = idx;
    }
}

// ---------------- CSR fill + inflsum (one edge pass) ----------------
__global__ void k_fill(const int* __restrict__ ei, int E,
                       const int* __restrict__ startp, int* __restrict__ cursor,
                       int* __restrict__ esrc,
                       const float* __restrict__ deg, float* __restrict__ inflsum) {
    int e = blockIdx.x * blockDim.x + threadIdx.x;
    if (e >= E) return;
    int s = ei[e], d = ei[E + e];
    int p = atomicAdd(&cursor[d], 1);
    esrc[startp[d] + 1 + p] = s;
    atomicAdd(&inflsum[s], deg[d]);
}

// ---------------- GAT: z = h@W (bf16 out), es/ed; || infl rider --------------
__global__ __attribute__((amdgpu_waves_per_eu(4, 4))) void __launch_bounds__(256)
k_z(const float* __restrict__ hbuf, const float* __restrict__ W,
    const float* __restrict__ asrc, const float* __restrict__ adst,
    uint* __restrict__ zbuf, float* __restrict__ es, float* __restrict__ ed,
    const float* __restrict__ deg, const float* __restrict__ inflsum,
    float* __restrict__ inflv, unsigned* __restrict__ scal,
    int N, int gZ) {
    int bid = blockIdx.x;
    if (bid >= gZ) {
        // structural infl + global maxes (rides on first k_z only)
        int idx = (bid - gZ) * blockDim.x + threadIdx.x;
        float dv = 0.f, iv = 0.f;
        if (idx < N) {
            dv = deg[idx];
            iv = dv > 0.f ? inflsum[idx] / dv : 0.f;
            inflv[idx] = iv;
        }
        float dm = dv, im = iv;
#pragma unroll
        for (int off = 32; off; off >>= 1) {
            dm = fmaxf(dm, __shfl_xor(dm, off, 64));
            im = fmaxf(im, __shfl_xor(im, off, 64));
        }
        if ((threadIdx.x & 63) == 0) {
            atomicMax(scal + 0, __float_as_uint(dm));
            atomicMax(scal + 1, __float_as_uint(im));
        }
        return;
    }
    int tid = bid * blockDim.x + threadIdx.x;
    int n = tid < N ? tid : N - 1;
    const float* hr = hbuf + (size_t)n * 64;
    float z[64];
#pragma unroll
    for (int j = 0; j < 64; ++j) z[j] = 0.f;
#pragma unroll 2
    for (int c = 0; c < 16; ++c) {
        float4 hv = *reinterpret_cast<const float4*>(hr + c * 4);
        const float* wb = W + c * 4 * 64;
#pragma unroll
        for (int j = 0; j < 64; ++j) {
            z[j] = fmaf(hv.x, wb[j], z[j]);
            z[j] = fmaf(hv.y, wb[64 + j], z[j]);
            z[j] = fmaf(hv.z, wb[128 + j], z[j]);
            z[j] = fmaf(hv.w, wb[192 + j], z[j]);
        }
    }
    float e0 = 0, e1 = 0, e2 = 0, e3 = 0, d0 = 0, d1 = 0, d2 = 0, d3 = 0;
#pragma unroll
    for (int j = 0; j < 64; j += 4) {
        e0 = fmaf(z[j], asrc[j], e0);
        e1 = fmaf(z[j + 1], asrc[j + 1], e1);
        e2 = fmaf(z[j + 2], asrc[j + 2], e2);
        e3 = fmaf(z[j + 3], asrc[j + 3], e3);
        d0 = fmaf(z[j], adst[j], d0);
        d1 = fmaf(z[j + 1], adst[j + 1], d1);
        d2 = fmaf(z[j + 2], adst[j + 2], d2);
        d3 = fmaf(z[j + 3], adst[j + 3], d3);
    }
    if (tid < N) {
        uint* zr = zbuf + (size_t)tid * 32;
#pragma unroll
        for (int c = 0; c < 8; ++c) {
            uint4 pv;
            pv.x = f2bf(z[c * 8 + 0]) | (f2bf(z[c * 8 + 1]) << 16);
            pv.y = f2bf(z[c * 8 + 2]) | (f2bf(z[c * 8 + 3]) << 16);
            pv.z = f2bf(z[c * 8 + 4]) | (f2bf(z[c * 8 + 5]) << 16);
            pv.w = f2bf(z[c * 8 + 6]) | (f2bf(z[c * 8 + 7]) << 16);
            *reinterpret_cast<uint4*>(zr + c * 4) = pv;
        }
        es[tid] = (e0 + e1) + (e2 + e3);
        ed[tid] = (d0 + d1) + (d2 + d3);
    }
}

// ---------------- fused GAT aggregation: quad-edge quarter-wave (bf16 z) -----
// Wave per dst node. 16 lanes x uint2 (4 bf16 features) per edge -> 4 edges
// in flight per gather instruction. Quarters combined via shfl_xor(16,32).
__global__ void k_agg(const int* __restrict__ start, const int* __restrict__ cnt,
                      const int* __restrict__ esrc,
                      const float* __restrict__ es, const float* __restrict__ ed,
                      const uint* __restrict__ zb,
                      const float* __restrict__ b, const float* __restrict__ g,
                      const float* __restrict__ bta, const float* __restrict__ mean,
                      const float* __restrict__ var,
                      float* __restrict__ hbuf, int N) {
    int wid  = (blockIdx.x * blockDim.x + threadIdx.x) >> 6;
    int lane = threadIdx.x & 63;
    if (wid >= N) return;
    int row0 = start[wid];
    int c    = cnt[wid] + 1;       // +1 self-loop
    float edn = ed[wid];
    int lq = lane & 15, q = lane >> 4;

    int   sreg = 0;
    float exv  = 0.f;
    if (lane < c) {
        sreg = esrc[row0 + lane];
        float e = es[sreg] + edn;
        e = e >= 0.f ? e : 0.2f * e;
        exv = __expf(e);
    }
    float ssum = exv;
    for (int k = 64 + lane; k < c; k += 64) {          // rare tail c>64
        int s = esrc[row0 + k];
        float e = es[s] + edn; e = e >= 0.f ? e : 0.2f * e;
        ssum += __expf(e);
    }
#pragma unroll
    for (int off = 32; off; off >>= 1) ssum += __shfl_xor(ssum, off, 64);

    float a0 = 0.f, a1 = 0.f, a2 = 0.f, a3 = 0.f;
    int kmax = c < 64 ? c : 64;
    for (int e = q; e < kmax; e += 4) {
        int   se = __shfl(sreg, e, 64);
        float we = __shfl(exv, e, 64);
        uint2 p = *reinterpret_cast<const uint2*>(zb + (size_t)se * 32 + lq * 2);
        a0 = fmaf(bflo(p.x), we, a0);
        a1 = fmaf(bfhi(p.x), we, a1);
        a2 = fmaf(bflo(p.y), we, a2);
        a3 = fmaf(bfhi(p.y), we, a3);
    }
    for (int e = 64; e < c; ++e) {                     // rare tail c>64
        int s = esrc[row0 + e];
        float ee = es[s] + edn; ee = ee >= 0.f ? ee : 0.2f * ee;
        float we = __expf(ee);
        if (q == 0) {
            uint2 p = *reinterpret_cast<const uint2*>(zb + (size_t)s * 32 + lq * 2);
            a0 = fmaf(bflo(p.x), we, a0);
            a1 = fmaf(bfhi(p.x), we, a1);
            a2 = fmaf(bflo(p.y), we, a2);
            a3 = fmaf(bfhi(p.y), we, a3);
        }
    }
    a0 += __shfl_xor(a0, 16, 64); a0 += __shfl_xor(a0, 32, 64);
    a1 += __shfl_xor(a1, 16, 64); a1 += __shfl_xor(a1, 32, 64);
    a2 += __shfl_xor(a2, 16, 64); a2 += __shfl_xor(a2, 32, 64);
    a3 += __shfl_xor(a3, 16, 64); a3 += __shfl_xor(a3, 32, 64);

    if (q == 0) {
        float inv = 1.f / ssum;
        float4 bb = reinterpret_cast<const float4*>(b)[lq];
        float4 gg = reinterpret_cast<const float4*>(g)[lq];
        float4 tt = reinterpret_cast<const float4*>(bta)[lq];
        float4 mm = reinterpret_cast<const float4*>(mean)[lq];
        float4 vv = reinterpret_cast<const float4*>(var)[lq];
        float v0 = (a0 * inv + bb.x - mm.x) * (gg.x * rsqrtf(vv.x + 1e-5f)) + tt.x;
        float v1 = (a1 * inv + bb.y - mm.y) * (gg.y * rsqrtf(vv.y + 1e-5f)) + tt.y;
        float v2 = (a2 * inv + bb.z - mm.z) * (gg.z * rsqrtf(vv.z + 1e-5f)) + tt.z;
        float v3 = (a3 * inv + bb.w - mm.w) * (gg.w * rsqrtf(vv.w + 1e-5f)) + tt.w;
        reinterpret_cast<float4*>(hbuf + (size_t)wid * 64)[lq] =
            make_float4(fmaxf(v0, 0.f), fmaxf(v1, 0.f), fmaxf(v2, 0.f), fmaxf(v3, 0.f));
    }
}

// ---------------- output head: lane = node ----------------
__global__ __attribute__((amdgpu_waves_per_eu(4, 4))) void __launch_bounds__(256)
k_final(const float* __restrict__ hbuf, const float* __restrict__ deg,
        const float* __restrict__ inflv, const unsigned* __restrict__ scal,
        const float* __restrict__ seW1, const float* __restrict__ seb1,
        const float* __restrict__ M2, const float* __restrict__ b2f,
        const float* __restrict__ oW1,
        const float* __restrict__ oW2, const float* __restrict__ ob2,
        const float* __restrict__ oW3, const float* __restrict__ ob3,
        float* __restrict__ out, int N) {
    int tid = blockIdx.x * blockDim.x + threadIdx.x;
    int n = tid < N ? tid : N - 1;

    float degmax  = fmaxf(__uint_as_float(scal[0]), 1.0f);
    float inflmax = fmaxf(__uint_as_float(scal[1]), 1e-12f);
    float nd = deg[n] / degmax;
    float fl = inflv[n] / inflmax;

    float hid[32];
#pragma unroll
    for (int k = 0; k < 32; ++k)
        hid[k] = fmaxf(fmaf(nd, seW1[k], fmaf(fl, seW1[64 + k], seb1[k])), 0.f);

    float o1[64];
#pragma unroll
    for (int j = 0; j < 64; ++j) o1[j] = b2f[j];
#pragma unroll 4
    for (int k = 0; k < 32; ++k) {
#pragma unroll
        for (int j = 0; j < 64; ++j)
            o1[j] = fmaf(hid[k], M2[k * 64 + j], o1[j]);
    }
    const float* hr = hbuf + (size_t)n * 64;
#pragma unroll 2
    for (int c = 0; c < 16; ++c) {
        float4 hv = *reinterpret_cast<const float4*>(hr + c * 4);
        const float* wb = oW1 + c * 4 * 64;
#pragma unroll
        for (int j = 0; j < 64; ++j) {
            o1[j] = fmaf(hv.x, wb[j], o1[j]);
            o1[j] = fmaf(hv.y, wb[64 + j], o1[j]);
            o1[j] = fmaf(hv.z, wb[128 + j], o1[j]);
            o1[j] = fmaf(hv.w, wb[192 + j], o1[j]);
        }
    }
#pragma unroll
    for (int j = 0; j < 64; ++j) o1[j] = fmaxf(o1[j], 0.f);

    float o2[32];
#pragma unroll
    for (int k = 0; k < 32; ++k) o2[k] = ob2[k];
#pragma unroll 4
    for (int j = 0; j < 64; ++j) {
#pragma unroll
        for (int k = 0; k < 32; ++k)
            o2[k] = fmaf(o1[j], oW2[j * 32 + k], o2[k]);
    }
    float a0 = 0, a1 = 0, a2 = 0, a3 = 0;
#pragma unroll
    for (int k = 0; k < 32; k += 4) {
        a0 = fmaf(fmaxf(o2[k], 0.f), oW3[k], a0);
        a1 = fmaf(fmaxf(o2[k + 1], 0.f), oW3[k + 1], a1);
        a2 = fmaf(fmaxf(o2[k + 2], 0.f), oW3[k + 2], a2);
        a3 = fmaf(fmaxf(o2[k + 3], 0.f), oW3[k + 3], a3);
    }
    if (tid < N)
        out[tid] = 1.f / (1.f + __expf(-((a0 + a1) + (a2 + a3) + ob3[0])));
}

// ---------------- launch ----------------
extern "C" void kernel_launch(void* const* d_in, const int* in_sizes, int n_in,
                              void* d_out, int out_size, void* d_ws, size_t ws_size,
                              hipStream_t stream) {
    const float* x     = (const float*)d_in[0];
    const int*   ei    = (const int*)d_in[1];
    const float* faW1  = (const float*)d_in[2];
    const float* fab1  = (const float*)d_in[3];
    const float* faW2  = (const float*)d_in[4];
    const float* fab2  = (const float*)d_in[5];
    const float* projW = (const float*)d_in[6];
    const float* projb = (const float*)d_in[7];
    const float* gatW  = (const float*)d_in[8];
    const float* gatAs = (const float*)d_in[9];
    const float* gatAd = (const float*)d_in[10];
    const float* gatB  = (const float*)d_in[11];
    const float* bnG   = (const float*)d_in[12];
    const float* bnB   = (const float*)d_in[13];
    const float* bnM   = (const float*)d_in[14];
    const float* bnV   = (const float*)d_in[15];
    const float* seW1  = (const float*)d_in[16];
    const float* seb1  = (const float*)d_in[17];
    const float* seW2  = (const float*)d_in[18];
    const float* seb2  = (const float*)d_in[19];
    const float* oW1   = (const float*)d_in[20];
    const float* ob1   = (const float*)d_in[21];
    const float* oW2   = (const float*)d_in[22];
    const float* ob2   = (const float*)d_in[23];
    const float* oW3   = (const float*)d_in[24];
    const float* ob3   = (const float*)d_in[25];
    float* out = (float*)d_out;

    const int N    = in_sizes[0] / 128;
    const int E    = in_sizes[1] / 2;
    const int Etot = E + N;

    float* ws      = (float*)d_ws;
    float* hbuf    = ws;
    uint*  zbuf    = (uint*)(hbuf + (size_t)N * 64);   // N*32 uints (bf16 pairs)
    float* es      = (float*)(zbuf + (size_t)N * 64);
    float* ed      = es + N;
    // ---- zero region (one memset) ----
    float* deg     = ed + N;
    float* inflsum = deg + N;
    unsigned* scal = (unsigned*)(inflsum + N);     // 8 slots
    int* cnt       = (int*)(scal + 8);
    int* cursor    = cnt + N;
    int* gcur      = cursor + N;                   // 8 slots
    // ---- end zero region ----
    int* startp    = gcur + 8;
    float* inflv   = (float*)(startp + N);
    int* esrc      = (int*)(inflv + N);            // Etot ints
    float* M2      = (float*)(esrc + Etot);        // 32*64
    float* b2f     = M2 + 32 * 64;                 // 64

    dim3 blk(256);
    int gN    = (N + 255) / 256;
    int gE    = (E + 255) / 256;
    int blkNW = (N * 64 + 255) / 256;              // wave-per-node (k_agg)

    hipMemsetAsync(deg, 0, ((size_t)4 * N + 16) * sizeof(float), stream);

    // stage 1: mlp || (deg,cnt) || prep
    k_fused1<<<gN + gE + 1, blk, 0, stream>>>(x, faW1, fab1, faW2, fab2, projW, projb,
                                              hbuf, N, ei, E, deg, cnt,
                                              seW2, seb2, oW1, ob1, M2, b2f, gN, gE);
    // stage 2: CSR alloc (+self-loop)
    k_alloc<<<gN, blk, 0, stream>>>(cnt, startp, esrc, gcur, N);
    // stage 3: CSR fill + inflsum (one edge pass)
    k_fill<<<gE, blk, 0, stream>>>(ei, E, startp, cursor, esrc, deg, inflsum);

    for (int l = 0; l < 3; ++l) {
        int extra = (l == 0) ? gN : 0;             // infl/scal rider on first k_z
        k_z<<<gN + extra, blk, 0, stream>>>(hbuf, gatW + l * 4096, gatAs + l * 64,
                                            gatAd + l * 64, zbuf, es, ed,
                                            deg, inflsum, inflv, scal, N, gN);
        k_agg<<<blkNW, blk, 0, stream>>>(startp, cnt, esrc, es, ed, zbuf,
                                         gatB + l * 64, bnG + l * 64, bnB + l * 64,
                                         bnM + l * 64, bnV + l * 64, hbuf, N);
    }

    k_final<<<gN, blk, 0, stream>>>(hbuf, deg, inflv, scal, seW1, seb1, M2, b2f,
                                    oW1, oW2, ob2, oW3, ob3, out, N);
}